// Round 3
// baseline (2572.168 us; speedup 1.0000x reference)
//
#include <hip/hip_runtime.h>
#include <math.h>

#define Bn 128
#define Tn 512
#define Dn 300
#define Hn 150
#define Gn 600   // 4*H
#define Ln 25

// ---------------- lengths from mask ----------------
__global__ __launch_bounds__(64) void k_len(const float* __restrict__ mask, int* __restrict__ lens) {
  int b = blockIdx.x, lane = threadIdx.x;
  float s = 0.f;
  for (int t = lane; t < Tn; t += 64) s += mask[b * Tn + t];
#pragma unroll
  for (int off = 32; off; off >>= 1) s += __shfl_xor(s, off);
  if (lane == 0) lens[b] = (int)(s + 0.5f);
}

// ---------------- input GEMM (chunked): stage CH rows of gate preactivations ----------------
// grid (Bn * CH/64 row-tiles, 20): blockIdx.y 0..9 -> fwd cols [y*64, ...), 10..19 -> bwd.
// fwd chunk starts at lo_f, bwd chunk at lo_b (descending across iterations).
__global__ __launch_bounds__(256) void k_gemm_in(
    const float* __restrict__ X, const float* __restrict__ Wf, const float* __restrict__ Wb,
    const float* __restrict__ bihf, const float* __restrict__ bhhf,
    const float* __restrict__ bihb, const float* __restrict__ bhhb,
    const int* __restrict__ lens, float* __restrict__ XgfC, float* __restrict__ YbC,
    int lo_f, int lo_b, int tshift, int chSh) {
  const int tileR = blockIdx.x;
  const int b = tileR >> tshift;
  const int tloc = (tileR & ((1 << tshift) - 1)) << 6;   // chunk-local row of tile start
  const int dir = (blockIdx.y >= 10);
  const int t_lo = dir ? lo_b : lo_f;
  const int t0g = t_lo + tloc;                            // global row of tile start
  if (t0g >= lens[b]) return;                             // block-uniform: whole tile dead
  const int c0 = (blockIdx.y - dir * 10) << 6;            // dir-local col tile start (0..576)

  __shared__ __align__(16) float As[16][64];              // [k][row]
  __shared__ __align__(16) float Bs[16][64];              // [k][col]
  const int tid = threadIdx.x;
  const int lr = tid >> 2;            // 0..63
  const int kg = (tid & 3) << 2;      // 0,4,8,12
  const int tx = tid & 15, ty = tid >> 4;
  float acc[4][4];
#pragma unroll
  for (int i = 0; i < 4; ++i)
#pragma unroll
    for (int j = 0; j < 4; ++j) acc[i][j] = 0.f;

  const float* Xrow = X + ((size_t)(b * Tn + t0g + lr)) * Dn;   // t0g+63 <= 511 always
  const int cgl = c0 + lr;                                       // 0..639
  const float* Wrow = (cgl < Gn) ? ((dir ? Wb : Wf) + (size_t)cgl * Dn) : nullptr;

  for (int k0 = 0; k0 < Dn; k0 += 16) {
    float4 av = make_float4(0.f, 0.f, 0.f, 0.f), bv = make_float4(0.f, 0.f, 0.f, 0.f);
    int k = k0 + kg;
    if (k < Dn) {                    // Dn=300, k%4==0 -> safe float4
      av = *(const float4*)(Xrow + k);
      if (Wrow) bv = *(const float4*)(Wrow + k);
    }
    __syncthreads();
    As[kg + 0][lr] = av.x; As[kg + 1][lr] = av.y; As[kg + 2][lr] = av.z; As[kg + 3][lr] = av.w;
    Bs[kg + 0][lr] = bv.x; Bs[kg + 1][lr] = bv.y; Bs[kg + 2][lr] = bv.z; Bs[kg + 3][lr] = bv.w;
    __syncthreads();
#pragma unroll
    for (int kk = 0; kk < 16; ++kk) {
      float4 a = *(const float4*)(&As[kk][ty << 2]);
      float4 q = *(const float4*)(&Bs[kk][tx << 2]);
      acc[0][0] = fmaf(a.x, q.x, acc[0][0]); acc[0][1] = fmaf(a.x, q.y, acc[0][1]);
      acc[0][2] = fmaf(a.x, q.z, acc[0][2]); acc[0][3] = fmaf(a.x, q.w, acc[0][3]);
      acc[1][0] = fmaf(a.y, q.x, acc[1][0]); acc[1][1] = fmaf(a.y, q.y, acc[1][1]);
      acc[1][2] = fmaf(a.y, q.z, acc[1][2]); acc[1][3] = fmaf(a.y, q.w, acc[1][3]);
      acc[2][0] = fmaf(a.z, q.x, acc[2][0]); acc[2][1] = fmaf(a.z, q.y, acc[2][1]);
      acc[2][2] = fmaf(a.z, q.z, acc[2][2]); acc[2][3] = fmaf(a.z, q.w, acc[2][3]);
      acc[3][0] = fmaf(a.w, q.x, acc[3][0]); acc[3][1] = fmaf(a.w, q.y, acc[3][1]);
      acc[3][2] = fmaf(a.w, q.z, acc[3][2]); acc[3][3] = fmaf(a.w, q.w, acc[3][3]);
    }
  }
  const int cg0 = c0 + (tx << 2);                 // dir-local col of this thread's 4-col group
  if (cg0 >= Gn) return;                          // dead col region (600..639), after barriers
  const float* bih = dir ? bihb : bihf;
  const float* bhh = dir ? bhhb : bhhf;
  float* out = dir ? YbC : XgfC;
  const size_t rowbase = ((size_t)b << chSh) + tloc;
#pragma unroll
  for (int i = 0; i < 4; ++i) {
    float4 r;
    r.x = acc[i][0] + bih[cg0 + 0] + bhh[cg0 + 0];
    r.y = acc[i][1] + bih[cg0 + 1] + bhh[cg0 + 1];
    r.z = acc[i][2] + bih[cg0 + 2] + bhh[cg0 + 2];
    r.w = acc[i][3] + bih[cg0 + 3] + bhh[cg0 + 3];
    *(float4*)(out + (rowbase + (ty << 2) + i) * Gn + cg0) = r;
  }
}

// ---------------- recurrent LSTM (chunked), one block per (batch, direction) ----------------
// 640 threads: threads 0..599 each own one gate column; all 150 Whh weights in VGPRs.
// (h,c) carried across chunk launches in sH/sC. LDS = 3 KB static.
__global__ __launch_bounds__(640) void k_lstm(
    const float* __restrict__ XgfC, const float* __restrict__ YbC,
    const float* __restrict__ Whf, const float* __restrict__ Whb,
    const int* __restrict__ lens, float* __restrict__ hf, float* __restrict__ hb,
    float* __restrict__ sHf, float* __restrict__ sCf,
    float* __restrict__ sHb, float* __restrict__ sCb,
    int lo_f, int lo_b, int chSh, int CH) {
  __shared__ __align__(16) float h_s[152];   // 150 + 2 zero pad for b128 reads
  __shared__ __align__(16) float g_s[Gn];
  const int tid = threadIdx.x;
  const int dir = blockIdx.x >> 7;
  const int b = blockIdx.x & 127;
  const int len = lens[b];
  const int lo = dir ? lo_b : lo_f;
  if (lo >= len) return;                      // block-uniform: no rows in this chunk
  const int hi = min(lo + CH, len);
  const float* Xg = dir ? YbC : XgfC;
  const float* W = dir ? Whb : Whf;
  float* ho = dir ? hb : hf;
  float* sH = dir ? sHb : sHf;
  float* sC = dir ? sCb : sCf;
  // sequence start: fwd begins at row 0 (lo==0); bwd begins at row len-1 (hi==len)
  const bool init = dir ? (hi == len) : (lo == 0);

  if (tid < 152) h_s[tid] = 0.f;
  float c = 0.f;
  if (!init && tid < Hn) { h_s[tid] = sH[b * Hn + tid]; c = sC[b * Hn + tid]; }

  const int col = tid;
  float wreg[152];
  if (col < Gn) {
    const float2* wr = (const float2*)(W + (size_t)col * Hn);   // col*600 bytes, 8B aligned
#pragma unroll
    for (int k = 0; k < 75; ++k) {
      float2 w2 = wr[k];
      wreg[2 * k] = w2.x; wreg[2 * k + 1] = w2.y;
    }
    wreg[150] = 0.f; wreg[151] = 0.f;
  } else {
#pragma unroll
    for (int k = 0; k < 152; ++k) wreg[k] = 0.f;
  }
  __syncthreads();

  const int nst = hi - lo;
  const size_t cb = ((size_t)b << chSh);      // chunk row base for this batch
  const size_t bT = (size_t)b * Tn;
  float xcur = 0.f;
  if (col < Gn) xcur = Xg[(cb + (dir ? (hi - 1 - lo) : 0)) * Gn + col];
  for (int s = 0; s < nst; ++s) {
    const int rl = dir ? (hi - 1 - lo - s) : s;   // chunk-local row
    const int rg = lo + rl;                        // global row
    float xn = 0.f;
    if (col < Gn && s + 1 < nst) {
      int rln = dir ? (rl - 1) : (rl + 1);
      xn = Xg[(cb + rln) * Gn + col];              // prefetch under this step's FMAs
    }
    if (col < Gn) {
      float acc = xcur;
#pragma unroll
      for (int q = 0; q < 38; ++q) {               // 38*4 = 152 (last 2 zero-pad)
        float4 h4 = *(const float4*)(h_s + (q << 2));   // broadcast read: conflict-free
        acc = fmaf(wreg[q * 4 + 0], h4.x, acc);
        acc = fmaf(wreg[q * 4 + 1], h4.y, acc);
        acc = fmaf(wreg[q * 4 + 2], h4.z, acc);
        acc = fmaf(wreg[q * 4 + 3], h4.w, acc);
      }
      g_s[col] = acc;
    }
    xcur = xn;
    __syncthreads();
    if (tid < Hn) {
      float gi = g_s[tid], gf = g_s[tid + 150], gg = g_s[tid + 300], go = g_s[tid + 450];
      float si = 1.f / (1.f + expf(-gi));
      float sf = 1.f / (1.f + expf(-gf));
      float so = 1.f / (1.f + expf(-go));
      c = sf * c + si * tanhf(gg);
      float h = so * tanhf(c);
      h_s[tid] = h;
      ho[(bT + rg) * Hn + tid] = h;                // bwd scatters to already-reversed layout
    }
    __syncthreads();
  }
  if (tid < Hn) { sH[b * Hn + tid] = h_s[tid]; sC[b * Hn + tid] = c; }
}

// ---------------- emissions: out = concat(hf,hb) @ Wl^T + bl (only t < len) ----------------
__global__ __launch_bounds__(256) void k_emis(
    const float* __restrict__ hf, const float* __restrict__ hb,
    const float* __restrict__ Wl, const float* __restrict__ bl,
    const int* __restrict__ lens, float* __restrict__ em) {
  int idx = blockIdx.x * 256 + threadIdx.x;
  int row = idx >> 5;
  int l = idx & 31;
  int b = row >> 9, t = row & 511;
  if (l >= Ln || t >= lens[b]) return;
  const float2* hf2 = (const float2*)(hf + (size_t)row * Hn);
  const float2* hb2 = (const float2*)(hb + (size_t)row * Hn);
  const float2* w0 = (const float2*)(Wl + (size_t)l * Dn);
  const float2* w1 = (const float2*)(Wl + (size_t)l * Dn + Hn);
  float acc = bl[l];
#pragma unroll 5
  for (int q = 0; q < 75; ++q) {
    float2 a = hf2[q], w = w0[q];
    acc = fmaf(a.x, w.x, fmaf(a.y, w.y, acc));
    float2 a2 = hb2[q], w2 = w1[q];
    acc = fmaf(a2.x, w2.x, fmaf(a2.y, w2.y, acc));
  }
  em[(size_t)row * Ln + l] = acc;
}

// ---------------- CRF numerator ----------------
__global__ __launch_bounds__(64) void k_num(
    const float* __restrict__ em, const int* __restrict__ labels, const int* __restrict__ lens,
    const float* __restrict__ trans, const float* __restrict__ st, const float* __restrict__ et,
    float* __restrict__ num) {
  int b = blockIdx.x, lane = threadIdx.x;
  int len = lens[b];
  float s = 0.f;
  for (int t = lane; t < len; t += 64) {
    int lab = labels[b * Tn + t];
    s += em[((size_t)b * Tn + t) * Ln + lab];
    if (t + 1 < len) s += trans[lab * Ln + labels[b * Tn + t + 1]];
  }
#pragma unroll
  for (int off = 32; off; off >>= 1) s += __shfl_xor(s, off);
  if (lane == 0)
    num[b] = s + st[labels[b * Tn]] + et[labels[b * Tn + len - 1]];
}

// ---------------- CRF denominator (forward logsumexp), one wave per batch ----------------
__global__ __launch_bounds__(64) void k_den(
    const float* __restrict__ em, const int* __restrict__ lens, const float* __restrict__ trans,
    const float* __restrict__ st, const float* __restrict__ et, float* __restrict__ den) {
  __shared__ float E[Ln * Ln];
  __shared__ float p_s[32];
  int b = blockIdx.x, lane = threadIdx.x;
  for (int u = lane; u < Ln * Ln; u += 64) E[u] = expf(trans[u]);
  int len = lens[b];
  const float* ob = em + (size_t)b * Tn * Ln;
  float alpha = -1e30f;
  if (lane < Ln) alpha = st[lane] + ob[lane];
  __syncthreads();
  for (int t = 1; t < len; ++t) {
    float m = alpha;
#pragma unroll
    for (int off = 32; off; off >>= 1) m = fmaxf(m, __shfl_xor(m, off));
    float p = (lane < Ln) ? expf(alpha - m) : 0.f;
    if (lane < 32) p_s[lane] = p;
    __syncthreads();
    if (lane < Ln) {
      float ssum = 0.f;
#pragma unroll
      for (int i = 0; i < Ln; ++i) ssum = fmaf(p_s[i], E[i * Ln + lane], ssum);
      alpha = m + logf(ssum) + ob[(size_t)t * Ln + lane];
    }
    __syncthreads();
  }
  float v = (lane < Ln) ? alpha + et[lane] : -1e30f;
  float m = v;
#pragma unroll
  for (int off = 32; off; off >>= 1) m = fmaxf(m, __shfl_xor(m, off));
  float ex = (lane < Ln) ? expf(v - m) : 0.f;
#pragma unroll
  for (int off = 32; off; off >>= 1) ex += __shfl_xor(ex, off);
  if (lane == 0) den[b] = m + logf(ex);
}

// ---------------- Viterbi: forward pass (bp in LDS) + backtrace, one wave per batch ----------------
__global__ __launch_bounds__(64) void k_vit(
    const float* __restrict__ em, const int* __restrict__ lens, const float* __restrict__ trans,
    const float* __restrict__ st, const float* __restrict__ et, float* __restrict__ pathf) {
  __shared__ float Tl[Ln * Ln];
  __shared__ float d_s[Ln];
  __shared__ unsigned char bp[Tn * Ln];   // 12.8 KB
  int b = blockIdx.x, lane = threadIdx.x;
  for (int u = lane; u < Ln * Ln; u += 64) Tl[u] = trans[u];
  int len = lens[b];
  const float* ob = em + (size_t)b * Tn * Ln;
  float delta = (lane < Ln) ? st[lane] + ob[lane] : -1e30f;
  __syncthreads();
  for (int t = 1; t < len; ++t) {
    if (lane < Ln) d_s[lane] = delta;
    __syncthreads();
    if (lane < Ln) {
      float best = -1e30f; int bi = 0;
#pragma unroll
      for (int i = 0; i < Ln; ++i) {            // ascending i + strict '>' = first-occurrence argmax
        float v = d_s[i] + Tl[i * Ln + lane];
        if (v > best) { best = v; bi = i; }
      }
      bp[t * Ln + lane] = (unsigned char)bi;
      delta = best + ob[(size_t)t * Ln + lane];
    }
    __syncthreads();
  }
  float v = (lane < Ln) ? delta + et[lane] : -1e30f;
  float m = v;
#pragma unroll
  for (int off = 32; off; off >>= 1) m = fmaxf(m, __shfl_xor(m, off));
  unsigned long long eq = __ballot(v == m);
  int last = __ffsll(eq) - 1;                   // lowest lane achieving max = jnp.argmax
  if (lane == 0) {
    int cur = last;
    for (int t = len - 1; t >= 1; --t) {
      pathf[b * Tn + t] = (float)cur;
      cur = bp[t * Ln + cur];
    }
    pathf[b * Tn + 0] = (float)cur;
  }
  for (int t = len + lane; t < Tn; t += 64)     // reference repeats trailing label past len
    pathf[b * Tn + t] = (float)last;
}

// ---------------- loss reduction ----------------
__global__ __launch_bounds__(64) void k_loss(const float* __restrict__ num, const float* __restrict__ den,
                                             float* __restrict__ out0) {
  int lane = threadIdx.x;
  float s = (num[lane] - den[lane]) + (num[lane + 64] - den[lane + 64]);
#pragma unroll
  for (int off = 32; off; off >>= 1) s += __shfl_xor(s, off);
  if (lane == 0) out0[0] = -s / (float)Bn;
}

extern "C" void kernel_launch(void* const* d_in, const int* in_sizes, int n_in,
                              void* d_out, int out_size, void* d_ws, size_t ws_size,
                              hipStream_t stream) {
  const float* X = (const float*)d_in[0];
  const float* mask = (const float*)d_in[1];
  const int* labels = (const int*)d_in[2];
  const float* Wihf = (const float*)d_in[3];
  const float* Whhf = (const float*)d_in[4];
  const float* bihf = (const float*)d_in[5];
  const float* bhhf = (const float*)d_in[6];
  const float* Wihb = (const float*)d_in[7];
  const float* Whhb = (const float*)d_in[8];
  const float* bihb = (const float*)d_in[9];
  const float* bhhb = (const float*)d_in[10];
  const float* Wl = (const float*)d_in[11];
  const float* bl = (const float*)d_in[12];
  const float* trans = (const float*)d_in[13];
  const float* st = (const float*)d_in[14];
  const float* et = (const float*)d_in[15];
  float* outv = (float*)d_out;

  // ws_size-adaptive staging: 1 chunk of 512 rows (400 MB) if it fits, else 8 chunks of 64 (125 MB).
  // Deterministic in ws_size -> identical work every call (graph-safe).
  auto planBytes = [](int CH) -> size_t {
    return ((size_t)2 * Bn * CH * Gn + 2 * (size_t)Bn * Tn * Hn + (size_t)Bn * Tn * Ln
            + 4 * (size_t)Bn * Hn + 3 * (size_t)Bn) * 4;
  };
  int CH, chSh, tshift;
  if (ws_size >= planBytes(512)) { CH = 512; chSh = 9; tshift = 3; }
  else                           { CH = 64;  chSh = 6; tshift = 0; }
  const int NC = Tn / CH;

  float* ws = (float*)d_ws;
  size_t off = 0;
  float* XgfC = ws + off; off += (size_t)Bn * CH * Gn;
  float* YbC  = ws + off; off += (size_t)Bn * CH * Gn;
  float* hf   = ws + off; off += (size_t)Bn * Tn * Hn;
  float* hb   = ws + off; off += (size_t)Bn * Tn * Hn;
  float* em   = ws + off; off += (size_t)Bn * Tn * Ln;
  float* sHf  = ws + off; off += (size_t)Bn * Hn;
  float* sCf  = ws + off; off += (size_t)Bn * Hn;
  float* sHb  = ws + off; off += (size_t)Bn * Hn;
  float* sCb  = ws + off; off += (size_t)Bn * Hn;
  float* num  = ws + off; off += Bn;
  float* den  = ws + off; off += Bn;
  int* lens   = (int*)(ws + off); off += Bn;

  k_len<<<Bn, 64, 0, stream>>>(mask, lens);

  for (int i = 0; i < NC; ++i) {
    int lo_f = i * CH;
    int lo_b = (NC - 1 - i) * CH;   // bwd consumes chunks in descending time order
    dim3 gg(Bn * (CH >> 6), 20);
    k_gemm_in<<<gg, 256, 0, stream>>>(X, Wihf, Wihb, bihf, bhhf, bihb, bhhb,
                                      lens, XgfC, YbC, lo_f, lo_b, tshift, chSh);
    k_lstm<<<2 * Bn, 640, 0, stream>>>(XgfC, YbC, Whhf, Whhb, lens, hf, hb,
                                       sHf, sCf, sHb, sCb, lo_f, lo_b, chSh, CH);
  }

  k_emis<<<(Bn * Tn * 32) / 256, 256, 0, stream>>>(hf, hb, Wl, bl, lens, em);

  k_num<<<Bn, 64, 0, stream>>>(em, labels, lens, trans, st, et, num);
  k_den<<<Bn, 64, 0, stream>>>(em, lens, trans, st, et, den);
  k_vit<<<Bn, 64, 0, stream>>>(em, lens, trans, st, et, outv + 1);
  k_loss<<<1, 64, 0, stream>>>(num, den, outv);
}

// Round 7
// 2136.137 us; speedup vs baseline: 1.2041x; 1.2041x over previous
//
#include <hip/hip_runtime.h>
#include <math.h>

#define Bn 128
#define Tn 512
#define Dn 300
#define Hn 150
#define Gn 600   // 4*H
#define Ln 25

// ---------------- lengths from mask ----------------
__global__ __launch_bounds__(64) void k_len(const float* __restrict__ mask, int* __restrict__ lens) {
  int b = blockIdx.x, lane = threadIdx.x;
  float s = 0.f;
  for (int t = lane; t < Tn; t += 64) s += mask[b * Tn + t];
#pragma unroll
  for (int off = 32; off; off >>= 1) s += __shfl_xor(s, off);
  if (lane == 0) lens[b] = (int)(s + 0.5f);
}

// ---------------- input GEMM (chunked, double-buffered LDS + prefetch) ----------------
// grid (Bn * CH/64 row-tiles, 20): blockIdx.y 0..9 -> fwd cols, 10..19 -> bwd.
// FMA order per output is bitwise-identical to the round-3 kernel; only staging changed.
__global__ __launch_bounds__(256) void k_gemm_in(
    const float* __restrict__ X, const float* __restrict__ Wf, const float* __restrict__ Wb,
    const float* __restrict__ bihf, const float* __restrict__ bhhf,
    const float* __restrict__ bihb, const float* __restrict__ bhhb,
    const int* __restrict__ lens, float* __restrict__ XgfC, float* __restrict__ YbC,
    int lo_f, int lo_b, int tshift, int chSh) {
  const int tileR = blockIdx.x;
  const int b = tileR >> tshift;
  const int tloc = (tileR & ((1 << tshift) - 1)) << 6;   // chunk-local row of tile start
  const int dir = (blockIdx.y >= 10);
  const int t_lo = dir ? lo_b : lo_f;
  const int t0g = t_lo + tloc;                            // global row of tile start
  if (t0g >= lens[b]) return;                             // block-uniform: whole tile dead
  const int c0 = (blockIdx.y - dir * 10) << 6;            // dir-local col tile start (0..576)

  __shared__ __align__(16) float As[2][16][64];           // [buf][k][row]  8 KB
  __shared__ __align__(16) float Bs[2][16][64];           // [buf][k][col]  8 KB
  const int tid = threadIdx.x;
  const int lr = tid >> 2;            // 0..63
  const int kg = (tid & 3) << 2;      // 0,4,8,12
  const int tx = tid & 15, ty = tid >> 4;
  float acc[4][4];
#pragma unroll
  for (int i = 0; i < 4; ++i)
#pragma unroll
    for (int j = 0; j < 4; ++j) acc[i][j] = 0.f;

  const float* Xrow = X + ((size_t)(b * Tn + t0g + lr)) * Dn;   // t0g+63 <= 511 always
  const int cgl = c0 + lr;                                       // 0..639
  const float* Wrow = (cgl < Gn) ? ((dir ? Wb : Wf) + (size_t)cgl * Dn) : nullptr;

  // initial load (k-slice 0)
  float4 av = make_float4(0.f, 0.f, 0.f, 0.f), bv = make_float4(0.f, 0.f, 0.f, 0.f);
  {
    int k = kg;                     // < 300 always
    av = *(const float4*)(Xrow + k);
    if (Wrow) bv = *(const float4*)(Wrow + k);
  }
  int buf = 0;
  for (int k0 = 0; k0 < Dn; k0 += 16) {
    As[buf][kg + 0][lr] = av.x; As[buf][kg + 1][lr] = av.y;
    As[buf][kg + 2][lr] = av.z; As[buf][kg + 3][lr] = av.w;
    Bs[buf][kg + 0][lr] = bv.x; Bs[buf][kg + 1][lr] = bv.y;
    Bs[buf][kg + 2][lr] = bv.z; Bs[buf][kg + 3][lr] = bv.w;
    __syncthreads();                // single barrier per k-slice (write->sync->read, dbuf)
    // prefetch next k-slice while FMAs run
    av = make_float4(0.f, 0.f, 0.f, 0.f); bv = make_float4(0.f, 0.f, 0.f, 0.f);
    int kn = k0 + 16 + kg;
    if (kn < Dn) {                  // Dn=300, kn%4==0 -> safe float4
      av = *(const float4*)(Xrow + kn);
      if (Wrow) bv = *(const float4*)(Wrow + kn);
    }
#pragma unroll
    for (int kk = 0; kk < 16; ++kk) {
      float4 a = *(const float4*)(&As[buf][kk][ty << 2]);
      float4 q = *(const float4*)(&Bs[buf][kk][tx << 2]);
      acc[0][0] = fmaf(a.x, q.x, acc[0][0]); acc[0][1] = fmaf(a.x, q.y, acc[0][1]);
      acc[0][2] = fmaf(a.x, q.z, acc[0][2]); acc[0][3] = fmaf(a.x, q.w, acc[0][3]);
      acc[1][0] = fmaf(a.y, q.x, acc[1][0]); acc[1][1] = fmaf(a.y, q.y, acc[1][1]);
      acc[1][2] = fmaf(a.y, q.z, acc[1][2]); acc[1][3] = fmaf(a.y, q.w, acc[1][3]);
      acc[2][0] = fmaf(a.z, q.x, acc[2][0]); acc[2][1] = fmaf(a.z, q.y, acc[2][1]);
      acc[2][2] = fmaf(a.z, q.z, acc[2][2]); acc[2][3] = fmaf(a.z, q.w, acc[2][3]);
      acc[3][0] = fmaf(a.w, q.x, acc[3][0]); acc[3][1] = fmaf(a.w, q.y, acc[3][1]);
      acc[3][2] = fmaf(a.w, q.z, acc[3][2]); acc[3][3] = fmaf(a.w, q.w, acc[3][3]);
    }
    buf ^= 1;
  }
  const int cg0 = c0 + (tx << 2);                 // dir-local col of this thread's 4-col group
  if (cg0 >= Gn) return;                          // dead col region, after all barriers
  const float* bih = dir ? bihb : bihf;
  const float* bhh = dir ? bhhb : bhhf;
  float* out = dir ? YbC : XgfC;
  const size_t rowbase = ((size_t)b << chSh) + tloc;
#pragma unroll
  for (int i = 0; i < 4; ++i) {
    float4 r;
    r.x = acc[i][0] + bih[cg0 + 0] + bhh[cg0 + 0];
    r.y = acc[i][1] + bih[cg0 + 1] + bhh[cg0 + 1];
    r.z = acc[i][2] + bih[cg0 + 2] + bhh[cg0 + 2];
    r.w = acc[i][3] + bih[cg0 + 3] + bhh[cg0 + 3];
    *(float4*)(out + (rowbase + (ty << 2) + i) * Gn + cg0) = r;
  }
}

// ---------------- recurrent LSTM (chunked), one block per (batch, direction) ----------------
__global__ __launch_bounds__(640) void k_lstm(
    const float* __restrict__ XgfC, const float* __restrict__ YbC,
    const float* __restrict__ Whf, const float* __restrict__ Whb,
    const int* __restrict__ lens, float* __restrict__ hf, float* __restrict__ hb,
    float* __restrict__ sHf, float* __restrict__ sCf,
    float* __restrict__ sHb, float* __restrict__ sCb,
    int lo_f, int lo_b, int chSh, int CH) {
  __shared__ __align__(16) float h_s[152];   // 150 + 2 zero pad for b128 reads
  __shared__ __align__(16) float g_s[Gn];
  const int tid = threadIdx.x;
  const int dir = blockIdx.x >> 7;
  const int b = blockIdx.x & 127;
  const int len = lens[b];
  const int lo = dir ? lo_b : lo_f;
  if (lo >= len) return;                      // block-uniform: no rows in this chunk
  const int hi = min(lo + CH, len);
  const float* Xg = dir ? YbC : XgfC;
  const float* W = dir ? Whb : Whf;
  float* ho = dir ? hb : hf;
  float* sH = dir ? sHb : sHf;
  float* sC = dir ? sCb : sCf;
  const bool init = dir ? (hi == len) : (lo == 0);

  if (tid < 152) h_s[tid] = 0.f;
  float c = 0.f;
  if (!init && tid < Hn) { h_s[tid] = sH[b * Hn + tid]; c = sC[b * Hn + tid]; }

  const int col = tid;
  float wreg[152];
  if (col < Gn) {
    const float2* wr = (const float2*)(W + (size_t)col * Hn);
#pragma unroll
    for (int k = 0; k < 75; ++k) {
      float2 w2 = wr[k];
      wreg[2 * k] = w2.x; wreg[2 * k + 1] = w2.y;
    }
    wreg[150] = 0.f; wreg[151] = 0.f;
  } else {
#pragma unroll
    for (int k = 0; k < 152; ++k) wreg[k] = 0.f;
  }
  __syncthreads();

  const int nst = hi - lo;
  const size_t cb = ((size_t)b << chSh);
  const size_t bT = (size_t)b * Tn;
  float xcur = 0.f;
  if (col < Gn) xcur = Xg[(cb + (dir ? (hi - 1 - lo) : 0)) * Gn + col];
  for (int s = 0; s < nst; ++s) {
    const int rl = dir ? (hi - 1 - lo - s) : s;   // chunk-local row
    const int rg = lo + rl;                        // global row
    float xn = 0.f;
    if (col < Gn && s + 1 < nst) {
      int rln = dir ? (rl - 1) : (rl + 1);
      xn = Xg[(cb + rln) * Gn + col];              // prefetch under this step's FMAs
    }
    if (col < Gn) {
      float acc = xcur;
#pragma unroll
      for (int q = 0; q < 38; ++q) {
        float4 h4 = *(const float4*)(h_s + (q << 2));   // broadcast read: conflict-free
        acc = fmaf(wreg[q * 4 + 0], h4.x, acc);
        acc = fmaf(wreg[q * 4 + 1], h4.y, acc);
        acc = fmaf(wreg[q * 4 + 2], h4.z, acc);
        acc = fmaf(wreg[q * 4 + 3], h4.w, acc);
      }
      g_s[col] = acc;
    }
    xcur = xn;
    __syncthreads();
    if (tid < Hn) {
      float gi = g_s[tid], gf = g_s[tid + 150], gg = g_s[tid + 300], go = g_s[tid + 450];
      float si = 1.f / (1.f + expf(-gi));
      float sf = 1.f / (1.f + expf(-gf));
      float so = 1.f / (1.f + expf(-go));
      c = sf * c + si * tanhf(gg);
      float h = so * tanhf(c);
      h_s[tid] = h;
      ho[(bT + rg) * Hn + tid] = h;
    }
    __syncthreads();
  }
  if (tid < Hn) { sH[b * Hn + tid] = h_s[tid]; sC[b * Hn + tid] = c; }
}

// ---------------- emissions: out = concat(hf,hb) @ Wl^T + bl (only t < len) ----------------
__global__ __launch_bounds__(256) void k_emis(
    const float* __restrict__ hf, const float* __restrict__ hb,
    const float* __restrict__ Wl, const float* __restrict__ bl,
    const int* __restrict__ lens, float* __restrict__ em) {
  int idx = blockIdx.x * 256 + threadIdx.x;
  int row = idx >> 5;
  int l = idx & 31;
  int b = row >> 9, t = row & 511;
  if (l >= Ln || t >= lens[b]) return;
  const float2* hf2 = (const float2*)(hf + (size_t)row * Hn);
  const float2* hb2 = (const float2*)(hb + (size_t)row * Hn);
  const float2* w0 = (const float2*)(Wl + (size_t)l * Dn);
  const float2* w1 = (const float2*)(Wl + (size_t)l * Dn + Hn);
  float acc = bl[l];
#pragma unroll 5
  for (int q = 0; q < 75; ++q) {
    float2 a = hf2[q], w = w0[q];
    acc = fmaf(a.x, w.x, fmaf(a.y, w.y, acc));
    float2 a2 = hb2[q], w2 = w1[q];
    acc = fmaf(a2.x, w2.x, fmaf(a2.y, w2.y, acc));
  }
  em[(size_t)row * Ln + l] = acc;
}

// ---------------- fused CRF: role 0 = denominator, 1 = viterbi, 2 = numerator ----------------
// grid 384 x 64 threads (1 wave). Wave-synchronous shuffles, em staged in LDS, trans column
// in 25 VGPRs (statically-unrolled indexing). Math order identical to the round-3 kernels.
__global__ __launch_bounds__(64) void k_crf(
    const float* __restrict__ em, const int* __restrict__ labels, const int* __restrict__ lens,
    const float* __restrict__ trans, const float* __restrict__ st, const float* __restrict__ et,
    float* __restrict__ den, float* __restrict__ num, float* __restrict__ pathf) {
  const int role = blockIdx.x >> 7;
  const int b = blockIdx.x & 127;
  const int lane = threadIdx.x;
  const int len = lens[b];

  if (role == 2) {                              // ---- numerator (unchanged math) ----
    float s = 0.f;
    for (int t = lane; t < len; t += 64) {
      int lab = labels[b * Tn + t];
      s += em[((size_t)b * Tn + t) * Ln + lab];
      if (t + 1 < len) s += trans[lab * Ln + labels[b * Tn + t + 1]];
    }
#pragma unroll
    for (int off = 32; off; off >>= 1) s += __shfl_xor(s, off);
    if (lane == 0)
      num[b] = s + st[labels[b * Tn]] + et[labels[b * Tn + len - 1]];
    return;
  }

  __shared__ __align__(16) float em_s[Tn * Ln];     // 51.2 KB
  __shared__ unsigned char bp[Tn * Ln];             // 12.8 KB (vit role only)

  // stage this batch's emission strip, coalesced float4 (em region has full Tn rows -> safe)
  const float* ob = em + (size_t)b * Tn * Ln;
  {
    const float4* ob4 = (const float4*)ob;
    float4* es4 = (float4*)em_s;
    int n4 = (len * Ln + 3) >> 2;                   // <= 3200
    for (int u = lane; u < n4; u += 64) es4[u] = ob4[u];
  }
  const int cl = (lane < Ln) ? lane : 0;            // clamped lane for safe indexing
  float col[Ln];
  if (role == 0) {
#pragma unroll
    for (int i = 0; i < Ln; ++i) col[i] = expf(trans[i * Ln + cl]);
  } else {
#pragma unroll
    for (int i = 0; i < Ln; ++i) col[i] = trans[i * Ln + cl];
  }
  __syncthreads();                                  // 1 wave: cheap, orders LDS stage

  if (role == 0) {                                  // ---- denominator ----
    float alpha = (lane < Ln) ? st[lane] + em_s[lane] : -1e30f;
    for (int t = 1; t < len; ++t) {
      float m = alpha;
#pragma unroll
      for (int off = 32; off; off >>= 1) m = fmaxf(m, __shfl_xor(m, off));
      float p = (lane < Ln) ? expf(alpha - m) : 0.f;
      float ssum = 0.f;
#pragma unroll
      for (int i = 0; i < Ln; ++i) ssum = fmaf(__shfl(p, i), col[i], ssum);
      float e_t = em_s[t * Ln + cl];
      alpha = (lane < Ln) ? m + logf(ssum) + e_t : -1e30f;
    }
    float v = (lane < Ln) ? alpha + et[lane] : -1e30f;
    float m = v;
#pragma unroll
    for (int off = 32; off; off >>= 1) m = fmaxf(m, __shfl_xor(m, off));
    float ex = (lane < Ln) ? expf(v - m) : 0.f;
#pragma unroll
    for (int off = 32; off; off >>= 1) ex += __shfl_xor(ex, off);
    if (lane == 0) den[b] = m + logf(ex);
    return;
  }

  // ---- viterbi ----
  float delta = (lane < Ln) ? st[lane] + em_s[lane] : -1e30f;
  for (int t = 1; t < len; ++t) {
    float best = -1e30f; int bi = 0;
#pragma unroll
    for (int i = 0; i < Ln; ++i) {                  // ascending i + strict '>' = first-occurrence
      float v = __shfl(delta, i) + col[i];
      if (v > best) { best = v; bi = i; }
    }
    if (lane < Ln) bp[t * Ln + lane] = (unsigned char)bi;
    delta = (lane < Ln) ? best + em_s[t * Ln + cl] : -1e30f;
  }
  float v = (lane < Ln) ? delta + et[lane] : -1e30f;
  float m = v;
#pragma unroll
  for (int off = 32; off; off >>= 1) m = fmaxf(m, __shfl_xor(m, off));
  unsigned long long eq = __ballot(v == m);
  int last = __ffsll(eq) - 1;                       // lowest lane achieving max = jnp.argmax
  __syncthreads();                                  // bp visible (1 wave: waitcnt)
  if (lane == 0) {
    int cur = last;
    for (int t = len - 1; t >= 1; --t) {
      pathf[b * Tn + t] = (float)cur;
      cur = bp[t * Ln + cur];
    }
    pathf[b * Tn + 0] = (float)cur;
  }
  for (int t = len + lane; t < Tn; t += 64)         // reference repeats trailing label past len
    pathf[b * Tn + t] = (float)last;
}

// ---------------- loss reduction ----------------
__global__ __launch_bounds__(64) void k_loss(const float* __restrict__ num, const float* __restrict__ den,
                                             float* __restrict__ out0) {
  int lane = threadIdx.x;
  float s = (num[lane] - den[lane]) + (num[lane + 64] - den[lane + 64]);
#pragma unroll
  for (int off = 32; off; off >>= 1) s += __shfl_xor(s, off);
  if (lane == 0) out0[0] = -s / (float)Bn;
}

extern "C" void kernel_launch(void* const* d_in, const int* in_sizes, int n_in,
                              void* d_out, int out_size, void* d_ws, size_t ws_size,
                              hipStream_t stream) {
  const float* X = (const float*)d_in[0];
  const float* mask = (const float*)d_in[1];
  const int* labels = (const int*)d_in[2];
  const float* Wihf = (const float*)d_in[3];
  const float* Whhf = (const float*)d_in[4];
  const float* bihf = (const float*)d_in[5];
  const float* bhhf = (const float*)d_in[6];
  const float* Wihb = (const float*)d_in[7];
  const float* Whhb = (const float*)d_in[8];
  const float* bihb = (const float*)d_in[9];
  const float* bhhb = (const float*)d_in[10];
  const float* Wl = (const float*)d_in[11];
  const float* bl = (const float*)d_in[12];
  const float* trans = (const float*)d_in[13];
  const float* st = (const float*)d_in[14];
  const float* et = (const float*)d_in[15];
  float* outv = (float*)d_out;

  // ws_size-adaptive chunking ladder; deterministic in ws_size -> graph-safe.
  auto planBytes = [](int CH) -> size_t {
    return ((size_t)2 * Bn * CH * Gn + 2 * (size_t)Bn * Tn * Hn + (size_t)Bn * Tn * Ln
            + 4 * (size_t)Bn * Hn + 3 * (size_t)Bn) * 4;
  };
  int CH, chSh;
  if      (ws_size >= planBytes(512)) { CH = 512; chSh = 9; }
  else if (ws_size >= planBytes(256)) { CH = 256; chSh = 8; }
  else if (ws_size >= planBytes(128)) { CH = 128; chSh = 7; }
  else                                { CH = 64;  chSh = 6; }
  const int tshift = chSh - 6;
  const int NC = Tn / CH;

  float* ws = (float*)d_ws;
  size_t off = 0;
  float* XgfC = ws + off; off += (size_t)Bn * CH * Gn;
  float* YbC  = ws + off; off += (size_t)Bn * CH * Gn;
  float* hf   = ws + off; off += (size_t)Bn * Tn * Hn;
  float* hb   = ws + off; off += (size_t)Bn * Tn * Hn;
  float* em   = ws + off; off += (size_t)Bn * Tn * Ln;
  float* sHf  = ws + off; off += (size_t)Bn * Hn;
  float* sCf  = ws + off; off += (size_t)Bn * Hn;
  float* sHb  = ws + off; off += (size_t)Bn * Hn;
  float* sCb  = ws + off; off += (size_t)Bn * Hn;
  float* num  = ws + off; off += Bn;
  float* den  = ws + off; off += Bn;
  int* lens   = (int*)(ws + off); off += Bn;

  k_len<<<Bn, 64, 0, stream>>>(mask, lens);

  for (int i = 0; i < NC; ++i) {
    int lo_f = i * CH;
    int lo_b = (NC - 1 - i) * CH;   // bwd consumes chunks in descending time order
    dim3 gg(Bn * (CH >> 6), 20);
    k_gemm_in<<<gg, 256, 0, stream>>>(X, Wihf, Wihb, bihf, bhhf, bihb, bhhb,
                                      lens, XgfC, YbC, lo_f, lo_b, tshift, chSh);
    k_lstm<<<2 * Bn, 640, 0, stream>>>(XgfC, YbC, Whhf, Whhb, lens, hf, hb,
                                       sHf, sCf, sHb, sCb, lo_f, lo_b, chSh, CH);
  }

  k_emis<<<(Bn * Tn * 32) / 256, 256, 0, stream>>>(hf, hb, Wl, bl, lens, em);

  k_crf<<<384, 64, 0, stream>>>(em, labels, lens, trans, st, et, den, num, outv + 1);
  k_loss<<<1, 64, 0, stream>>>(num, den, outv);
}